// Round 1
// baseline (43.237 us; speedup 1.0000x reference)
//
#include <hip/hip_runtime.h>
#include <hip/hip_bf16.h>
#include <math.h>

#define NCELL 32
#define P 128
#define C 4
#define HID 512
#define HEADS 4
#define HD 128
#define KSEL 64
#define THRESH 0.7f
#define NEGV -1e9f

__global__ __launch_bounds__(128) void pillar_attn_sample_kernel(
    const float* __restrict__ pts,      // [NCELL][P][C]
    const void*  __restrict__ maskp,    // [NCELL][P]  (dtype sniffed)
    const float* __restrict__ pos,      // [P][C]
    const float* __restrict__ q_w, const float* __restrict__ q_b,
    const float* __restrict__ k_w, const float* __restrict__ k_b,
    const float* __restrict__ v_w, const float* __restrict__ v_b,
    const float* __restrict__ w_w, const float* __restrict__ w_b,
    float* __restrict__ out)            // [NCELL*KSEL*C] ++ [NCELL*KSEL]
{
  __shared__ float ww[HID];
  __shared__ float G[C][16];     // masked q_w . w_w   [c][m*4+n]
  __shared__ float G0[16];       // masked q_b . w_w   [m*4+n]
  __shared__ float WU[HEADS];    // sum of w_w over !mask
  __shared__ float KV[16][16];   // k_w . v_w          [c*4+d][m*4+n]
  __shared__ float KB1[C][16];   // k_w . v_b
  __shared__ float KB2[C][16];   // k_b . v_w
  __shared__ float KB0[16];      // k_b . v_b
  __shared__ float VS[C][HEADS]; // row-sums of v_w
  __shared__ float VB[HEADS];    // row-sums of v_b
  __shared__ float wbuf[P];
  __shared__ unsigned char selb[P];
  __shared__ unsigned char mb[P];
  __shared__ int slotp[KSEL];
  __shared__ int s_cnt, s_fv, s_hv;

  const int cell = blockIdx.x;
  const int t = threadIdx.x;
  const int p = t;

  // ---- mask dtype detection (uniform across threads) ----
  // int32 0/1 words or f32 0/1.0 words -> 4-byte elems; else byte bool.
  int mkind;
  {
    const unsigned* u = (const unsigned*)maskp;
    bool i32ok = true, f32ok = true;
    for (int k = 0; k < 8; ++k) {
      unsigned v = u[k];
      if (v != 0u && v != 1u) i32ok = false;
      if (v != 0u && v != 0x3f800000u) f32ok = false;
    }
    mkind = (i32ok || f32ok) ? 0 : 1;
  }

  // ---- stage w_w and this cell's mask into LDS ----
  for (int k = t; k < HID; k += 128) ww[k] = w_w[k];
  {
    bool mv;
    if (mkind == 0) mv = ((const unsigned*)maskp)[cell * P + t] != 0u;
    else            mv = ((const unsigned char*)maskp)[cell * P + t] != 0;
    mb[t] = mv ? 1 : 0;
  }
  __syncthreads();

  // ---- phase 1: mask-dependent per-cell reductions ----
  if (t < 64) {                       // G[c][m][n]
    int c = t >> 4, m = (t >> 2) & 3, n = t & 3;
    const float* qr = q_w + c * HID + m * HD;
    const float* wr = ww + n * HD;
    float s = 0.f;
    for (int i = 0; i < P; ++i) if (mb[i]) s += qr[i] * wr[i];
    G[c][m * 4 + n] = s;
  } else if (t < 80) {                // G0[m][n]
    int e = t - 64; int m = e >> 2, n = e & 3;
    const float* qr = q_b + m * HD;
    const float* wr = ww + n * HD;
    float s = 0.f;
    for (int i = 0; i < P; ++i) if (mb[i]) s += qr[i] * wr[i];
    G0[m * 4 + n] = s;
  } else if (t < 84) {                // WU[n]
    int n = t - 80;
    const float* wr = ww + n * HD;
    float s = 0.f;
    for (int i = 0; i < P; ++i) if (!mb[i]) s += wr[i];
    WU[n] = s;
  }

  // ---- phase 2: mask-independent reductions (global reads only) ----
  for (int e = t; e < 256; e += 128) { // KV[c][d][m][n], 2 per thread
    int c = e >> 6, d = (e >> 4) & 3, m = (e >> 2) & 3, n = e & 3;
    const float* kr = k_w + c * HID + m * HD;
    const float* vr = v_w + d * HID + n * HD;
    float s = 0.f;
    for (int j = 0; j < HD; ++j) s += kr[j] * vr[j];
    KV[c * 4 + d][m * 4 + n] = s;
  }
  if (t < 64) {                       // KB1[c][m][n]
    int c = t >> 4, m = (t >> 2) & 3, n = t & 3;
    const float* kr = k_w + c * HID + m * HD;
    const float* vr = v_b + n * HD;
    float s = 0.f;
    for (int j = 0; j < HD; ++j) s += kr[j] * vr[j];
    KB1[c][m * 4 + n] = s;
  } else {                            // KB2[d][m][n]
    int e = t - 64;
    int d = e >> 4, m = (e >> 2) & 3, n = e & 3;
    const float* kr = k_b + m * HD;
    const float* vr = v_w + d * HID + n * HD;
    float s = 0.f;
    for (int j = 0; j < HD; ++j) s += kr[j] * vr[j];
    KB2[d][m * 4 + n] = s;
  }
  if (t < 16) {                       // KB0[m][n]
    int m = t >> 2, n = t & 3;
    const float* kr = k_b + m * HD;
    const float* vr = v_b + n * HD;
    float s = 0.f;
    for (int j = 0; j < HD; ++j) s += kr[j] * vr[j];
    KB0[m * 4 + n] = s;
  } else if (t < 32) {                // VS[d][n]
    int e = t - 16; int d = e >> 2, n = e & 3;
    const float* vr = v_w + d * HID + n * HD;
    float s = 0.f;
    for (int j = 0; j < HD; ++j) s += vr[j];
    VS[d][n] = s;
  } else if (t < 36) {                // VB[n]
    int n = t - 32;
    const float* vr = v_b + n * HD;
    float s = 0.f;
    for (int j = 0; j < HD; ++j) s += vr[j];
    VB[n] = s;
  }
  __syncthreads();

  // ---- phase 3: per-point score S_p and weight ----
  float x[C];
  for (int c = 0; c < C; ++c) x[c] = pts[(cell * P + p) * C + c] + pos[p * C + c];

  float t1 = 0.f;
  for (int mn = 0; mn < 16; ++mn) {
    float A = G0[mn];
    for (int c = 0; c < C; ++c) A += x[c] * G[c][mn];
    float Bv = KB0[mn];
    for (int c = 0; c < C; ++c) Bv += x[c] * (KB1[c][mn] + KB2[c][mn]);
    for (int c = 0; c < C; ++c)
      for (int d = 0; d < C; ++d) Bv += x[c] * x[d] * KV[c * 4 + d][mn];
    t1 += A * Bv;
  }
  const float scale = 0.0883883476483184f; // 1/sqrt(128)
  float t2 = 0.f;
  for (int n = 0; n < HEADS; ++n) {
    float sv = VB[n];
    for (int d = 0; d < C; ++d) sv += x[d] * VS[d][n];
    t2 += WU[n] * sv;
  }
  float S = t1 * scale + NEGV * t2 + w_b[0];
  float sig = 1.f / (1.f + expf(-S));
  float wv = mb[p] ? sig : 0.f;
  wbuf[p] = wv;
  selb[p] = (wv > THRESH && mb[p]) ? 1 : 0;
  if (t < KSEL) slotp[t] = -1;
  if (t == 0) {
    int fv = 0, hv = 0;
    for (int q = 0; q < P; ++q) { if (mb[q]) { fv = q; hv = 1; break; } }
    s_fv = fv; s_hv = hv;
  }
  __syncthreads();

  // ---- phase 4: count + ranks (each thread scans all 128) ----
  {
    int cnt = 0, rank_asc = 0, rank_top = 0;
    float wp = wbuf[p];
    for (int q = 0; q < P; ++q) {
      if (selb[q]) {
        ++cnt;
        if (q < p) ++rank_asc;
        float wq = wbuf[q];
        if (wq > wp || (wq == wp && q < p)) ++rank_top;  // lax.top_k tie-break
      }
    }
    int rank = (cnt > KSEL) ? rank_top : rank_asc;
    if (selb[p] && rank < KSEL) slotp[rank] = p;
    if (t == 0) s_cnt = cnt;
  }
  __syncthreads();

  // ---- phase 5: write outputs (all 64 slots, zeros where invalid) ----
  float* out_pts = out;                       // [NCELL][KSEL][C]
  float* out_w   = out + NCELL * KSEL * C;    // [NCELL][KSEL]
  if (t < KSEL) {
    int k = t;
    int cnt_ = s_cnt;
    float pw = 0.f;
    float pv[C] = {0.f, 0.f, 0.f, 0.f};
    if (cnt_ == 0) {
      if (k == 0 && s_hv) {
        int p0 = s_fv;
        for (int c = 0; c < C; ++c) pv[c] = pts[(cell * P + p0) * C + c];
        pw = wbuf[p0];
      }
    } else {
      int nval = cnt_ < KSEL ? cnt_ : KSEL;
      if (k < nval) {
        int p0 = slotp[k];
        for (int c = 0; c < C; ++c) pv[c] = pts[(cell * P + p0) * C + c];
        pw = wbuf[p0];
      }
    }
    for (int c = 0; c < C; ++c) out_pts[(cell * KSEL + k) * C + c] = pv[c];
    out_w[cell * KSEL + k] = pw;
  }
}

extern "C" void kernel_launch(void* const* d_in, const int* in_sizes, int n_in,
                              void* d_out, int out_size, void* d_ws, size_t ws_size,
                              hipStream_t stream) {
  const float* pts  = (const float*)d_in[0];
  const void*  msk  = (const void*)d_in[1];
  const float* pos  = (const float*)d_in[2];
  const float* q_w  = (const float*)d_in[3];
  const float* q_b  = (const float*)d_in[4];
  const float* k_w  = (const float*)d_in[5];
  const float* k_b  = (const float*)d_in[6];
  const float* v_w  = (const float*)d_in[7];
  const float* v_b  = (const float*)d_in[8];
  const float* w_w  = (const float*)d_in[9];
  const float* w_b  = (const float*)d_in[10];
  float* out = (float*)d_out;

  pillar_attn_sample_kernel<<<NCELL, 128, 0, stream>>>(
      pts, msk, pos, q_w, q_b, k_w, k_b, v_w, v_b, w_w, w_b, out);
}

// Round 2
// 23.445 us; speedup vs baseline: 1.8442x; 1.8442x over previous
//
#include <hip/hip_runtime.h>
#include <hip/hip_bf16.h>
#include <math.h>

#define NCELL 32
#define P 128
#define C 4
#define HID 512
#define KSEL 64
#define THRESH 0.7f
#define NEGV -1e9f

__global__ __launch_bounds__(128) void pillar_attn_sample_kernel(
    const float* __restrict__ pts,      // [NCELL][P][C]
    const void*  __restrict__ maskp,    // [NCELL][P]  (dtype sniffed)
    const float* __restrict__ pos,      // [P][C]
    const float* __restrict__ q_w, const float* __restrict__ q_b,
    const float* __restrict__ k_w, const float* __restrict__ k_b,
    const float* __restrict__ v_w, const float* __restrict__ v_b,
    const float* __restrict__ w_w, const float* __restrict__ w_b,
    float* __restrict__ out)            // [NCELL*KSEL*C] ++ [NCELL*KSEL]
{
  // ---- LDS ----
  __shared__ __align__(16) float sQ[2048];   // q_w  [4][512]
  __shared__ __align__(16) float sK[2048];   // k_w
  __shared__ __align__(16) float sV[2048];   // v_w
  __shared__ __align__(16) float sWW[512];   // w_w
  __shared__ __align__(16) float sQB[512];   // q_b
  __shared__ __align__(16) float sKB[512];   // k_b
  __shared__ __align__(16) float sVB[512];   // v_b
  __shared__ __align__(16) float sWM[512];   // masked w_w
  __shared__ __align__(16) float sONE[128];  // ones (rowsum-as-dot)
  __shared__ float R[512];                   // dot results
  __shared__ float wbuf[P];
  __shared__ unsigned char selb[P];
  __shared__ unsigned char mb[P];
  __shared__ int slotp[KSEL];
  __shared__ int s_cnt, s_fv;

  const int cell = blockIdx.x;
  const int t = threadIdx.x;
  const int p = t;

  // ---- mask dtype detection (uniform) ----
  int mkind;
  {
    const unsigned* u = (const unsigned*)maskp;
    bool i32ok = true, f32ok = true;
    for (int k = 0; k < 8; ++k) {
      unsigned v = u[k];
      if (v != 0u && v != 1u) i32ok = false;
      if (v != 0u && v != 0x3f800000u) f32ok = false;
    }
    mkind = (i32ok || f32ok) ? 0 : 1;
  }

  // ---- stage weights into LDS (coalesced float4) ----
  {
    const float4* q4 = (const float4*)q_w;
    const float4* k4 = (const float4*)k_w;
    const float4* v4 = (const float4*)v_w;
    float4* sQ4 = (float4*)sQ; float4* sK4 = (float4*)sK; float4* sV4 = (float4*)sV;
    #pragma unroll
    for (int i = 0; i < 4; ++i) {
      int idx = t + i * 128;                 // 512 float4 per 2048-float array
      sQ4[idx] = q4[idx];
      sK4[idx] = k4[idx];
      sV4[idx] = v4[idx];
    }
    ((float4*)sWW)[t] = ((const float4*)w_w)[t];   // 128 float4
    ((float4*)sQB)[t] = ((const float4*)q_b)[t];
    ((float4*)sKB)[t] = ((const float4*)k_b)[t];
    ((float4*)sVB)[t] = ((const float4*)v_b)[t];
  }
  bool mv;
  if (mkind == 0) mv = ((const unsigned*)maskp)[cell * P + t] != 0u;
  else            mv = ((const unsigned char*)maskp)[cell * P + t] != 0;
  mb[t] = mv ? 1 : 0;
  if (t == 0) s_fv = P;
  __syncthreads();

  // ---- masked w_w copy + ones row ----
  #pragma unroll
  for (int n = 0; n < 4; ++n) sWM[n * 128 + t] = mv ? sWW[n * 128 + t] : 0.f;
  sONE[t] = 1.f;
  __syncthreads();

  // ---- 508 length-128 dots, 4 tasks/thread ----
  // 0..255   KV  [c][d][m][n] : K(c,m) . V(d,n)
  // 256..319 KB1 [c][m][n]    : K(c,m) . VB(n)
  // 320..383 KB2 [d][m][n]    : KB(m)  . V(d,n)
  // 384..399 KB0 [m][n]       : KB(m)  . VB(n)
  // 400..463 G   [c][m][n]    : Q(c,m) . WM(n)
  // 464..479 G0  [m][n]       : QB(m)  . WM(n)
  // 480..495 VS  [d][n]       : V(d,n) . 1
  // 496..499 VB  [n]          : VB(n)  . 1
  // 500..503 WWs [n]          : WW(n)  . 1
  // 504..507 WMs [n]          : WM(n)  . 1
  for (int task = t; task < 508; task += 128) {
    const float* ra; const float* rb;
    if (task < 256) {
      int c = task >> 6, d = (task >> 4) & 3, mn = task & 15;
      ra = sK + c * 512 + (mn >> 2) * 128; rb = sV + d * 512 + (mn & 3) * 128;
    } else if (task < 320) {
      int e = task - 256; int c = e >> 4, mn = e & 15;
      ra = sK + c * 512 + (mn >> 2) * 128; rb = sVB + (mn & 3) * 128;
    } else if (task < 384) {
      int e = task - 320; int d = e >> 4, mn = e & 15;
      ra = sKB + (mn >> 2) * 128; rb = sV + d * 512 + (mn & 3) * 128;
    } else if (task < 400) {
      int mn = task - 384; ra = sKB + (mn >> 2) * 128; rb = sVB + (mn & 3) * 128;
    } else if (task < 464) {
      int e = task - 400; int c = e >> 4, mn = e & 15;
      ra = sQ + c * 512 + (mn >> 2) * 128; rb = sWM + (mn & 3) * 128;
    } else if (task < 480) {
      int mn = task - 464; ra = sQB + (mn >> 2) * 128; rb = sWM + (mn & 3) * 128;
    } else if (task < 496) {
      int e = task - 480; ra = sV + (e >> 2) * 512 + (e & 3) * 128; rb = sONE;
    } else if (task < 500) {
      ra = sVB + (task - 496) * 128; rb = sONE;
    } else if (task < 504) {
      ra = sWW + (task - 500) * 128; rb = sONE;
    } else {
      ra = sWM + (task - 504) * 128; rb = sONE;
    }
    const float4* a4 = (const float4*)ra;
    const float4* b4 = (const float4*)rb;
    float s0 = 0.f, s1 = 0.f, s2 = 0.f, s3 = 0.f;
    int rot = t & 31;
    #pragma unroll
    for (int kk = 0; kk < 32; ++kk) {
      int k = (kk + rot) & 31;
      float4 av = a4[k], bv = b4[k];
      s0 += av.x * bv.x; s1 += av.y * bv.y;
      s2 += av.z * bv.z; s3 += av.w * bv.w;
    }
    R[task] = (s0 + s1) + (s2 + s3);
  }
  __syncthreads();

  // ---- per-point score ----
  float4 pv4 = ((const float4*)pts)[cell * P + p];
  float4 po4 = ((const float4*)pos)[p];
  float x[C] = {pv4.x + po4.x, pv4.y + po4.y, pv4.z + po4.z, pv4.w + po4.w};

  float t1 = 0.f;
  #pragma unroll
  for (int mn = 0; mn < 16; ++mn) {
    float A = R[464 + mn];
    #pragma unroll
    for (int c = 0; c < C; ++c) A += x[c] * R[400 + (c << 4) + mn];
    float Bv = R[384 + mn];
    #pragma unroll
    for (int c = 0; c < C; ++c) Bv += x[c] * (R[256 + (c << 4) + mn] + R[320 + (c << 4) + mn]);
    #pragma unroll
    for (int c = 0; c < C; ++c)
      #pragma unroll
      for (int d = 0; d < C; ++d) Bv += x[c] * x[d] * R[(c << 6) + (d << 4) + mn];
    t1 += A * Bv;
  }
  const float scale = 0.0883883476483184f; // 1/sqrt(128)
  float t2 = 0.f;
  #pragma unroll
  for (int n = 0; n < 4; ++n) {
    float sv = R[496 + n];
    #pragma unroll
    for (int d = 0; d < C; ++d) sv += x[d] * R[480 + (d << 2) + n];
    t2 += (R[500 + n] - R[504 + n]) * sv;
  }
  float S = t1 * scale + NEGV * t2 + w_b[0];
  float sig = 1.f / (1.f + expf(-S));
  float wv = mv ? sig : 0.f;
  wbuf[p] = wv;
  selb[p] = (wv > THRESH && mv) ? 1 : 0;
  if (mv) atomicMin(&s_fv, p);
  __syncthreads();

  // ---- count + ranks (broadcast LDS scans) ----
  {
    int cnt = 0, rank_asc = 0, rank_top = 0;
    float wp = wbuf[p];
    for (int q = 0; q < P; ++q) {
      if (selb[q]) {
        ++cnt;
        if (q < p) ++rank_asc;
        float wq = wbuf[q];
        if (wq > wp || (wq == wp && q < p)) ++rank_top;  // lax.top_k tie-break
      }
    }
    int rank = (cnt > KSEL) ? rank_top : rank_asc;
    if (selb[p] && rank < KSEL) slotp[rank] = p;
    if (t == 0) s_cnt = cnt;
  }
  __syncthreads();

  // ---- write outputs ----
  float* out_pts = out;                       // [NCELL][KSEL][C]
  float* out_w   = out + NCELL * KSEL * C;    // [NCELL][KSEL]
  if (t < KSEL) {
    int k = t;
    int cnt_ = s_cnt;
    float pw = 0.f;
    float4 pvo = {0.f, 0.f, 0.f, 0.f};
    if (cnt_ == 0) {
      if (k == 0 && s_fv < P) {
        pvo = ((const float4*)pts)[cell * P + s_fv];
        pw = wbuf[s_fv];
      }
    } else {
      int nval = cnt_ < KSEL ? cnt_ : KSEL;
      if (k < nval) {
        int p0 = slotp[k];
        pvo = ((const float4*)pts)[cell * P + p0];
        pw = wbuf[p0];
      }
    }
    ((float4*)out_pts)[cell * KSEL + k] = pvo;
    out_w[cell * KSEL + k] = pw;
  }
}

extern "C" void kernel_launch(void* const* d_in, const int* in_sizes, int n_in,
                              void* d_out, int out_size, void* d_ws, size_t ws_size,
                              hipStream_t stream) {
  const float* pts  = (const float*)d_in[0];
  const void*  msk  = (const void*)d_in[1];
  const float* pos  = (const float*)d_in[2];
  const float* q_w  = (const float*)d_in[3];
  const float* q_b  = (const float*)d_in[4];
  const float* k_w  = (const float*)d_in[5];
  const float* k_b  = (const float*)d_in[6];
  const float* v_w  = (const float*)d_in[7];
  const float* v_b  = (const float*)d_in[8];
  const float* w_w  = (const float*)d_in[9];
  const float* w_b  = (const float*)d_in[10];
  float* out = (float*)d_out;

  pillar_attn_sample_kernel<<<NCELL, 128, 0, stream>>>(
      pts, msk, pos, q_w, q_b, k_w, k_b, v_w, v_b, w_w, w_b, out);
}